// Round 1
// baseline (981.063 us; speedup 1.0000x reference)
//
#include <hip/hip_runtime.h>

typedef __attribute__((ext_vector_type(8))) short s8v;
typedef __attribute__((ext_vector_type(4))) short s4v;
typedef __attribute__((ext_vector_type(4))) float f4v;

__device__ __forceinline__ unsigned short f2bf(float f) {
  unsigned int u = __float_as_uint(f);
  u += 0x7FFFu + ((u >> 16) & 1u);   // RNE
  return (unsigned short)(u >> 16);
}
__device__ __forceinline__ float bf2f(unsigned short s) {
  return __uint_as_float(((unsigned int)s) << 16);
}

// ---------------------------------------------------------------------------
// GEMM1: qkv = X @ [Wq|Wk|Wv] + bias, q-part normalized per head * gamma.
// X fp32 [65536,512]; W* fp32 [512,512]; out bf16 [65536,1536] (q|k|v).
// 128x128 tile, BK=64, 4 waves, mfma_f32_16x16x32_bf16.
// ---------------------------------------------------------------------------
__global__ __launch_bounds__(256, 2)
void gemm_qkv_kernel(const float* __restrict__ X,
                     const float* __restrict__ Wq, const float* __restrict__ bq,
                     const float* __restrict__ Wk, const float* __restrict__ bk,
                     const float* __restrict__ Wv, const float* __restrict__ bv,
                     const float* __restrict__ gamma,
                     unsigned short* __restrict__ qkv)
{
  __shared__ short As[128][72];   // [m][k] bf16, +8 pad -> 2-way bank conflict (free)
  __shared__ short Bs[128][72];   // [n][k] bf16 (transposed)
  const int t = threadIdx.x;
  const int rb = blockIdx.x, nb = blockIdx.y;
  const int wave = t >> 6, lane = t & 63;
  const int wm = wave & 1, wn = wave >> 1;
  const int quad = lane >> 4, l16 = lane & 15;
  const int row0 = rb * 128;

  const float* Wsrc; const float* bsrc; int ncol0;
  if (nb < 4)      { Wsrc = Wq; bsrc = bq; ncol0 = nb * 128; }
  else if (nb < 8) { Wsrc = Wk; bsrc = bk; ncol0 = (nb - 4) * 128; }
  else             { Wsrc = Wv; bsrc = bv; ncol0 = (nb - 8) * 128; }

  f4v acc[4][4];
  #pragma unroll
  for (int i = 0; i < 4; ++i)
    #pragma unroll
    for (int j = 0; j < 4; ++j) acc[i][j] = (f4v){0.f, 0.f, 0.f, 0.f};

  for (int kt = 0; kt < 512; kt += 64) {
    __syncthreads();
    // stage A: 128x64 fp32 -> bf16 (coalesced float4 loads)
    #pragma unroll
    for (int i = 0; i < 8; ++i) {
      int idx = i * 256 + t;          // 0..2047
      int m = idx >> 4;               // 16 float4 per 64-col row
      int k4 = (idx & 15) << 2;
      float4 xv = *(const float4*)&X[(size_t)(row0 + m) * 512 + kt + k4];
      s4v p = (s4v){ (short)f2bf(xv.x), (short)f2bf(xv.y),
                     (short)f2bf(xv.z), (short)f2bf(xv.w) };
      *(s4v*)&As[m][k4] = p;
    }
    // stage B: 64x128 fp32 -> bf16, transposed into Bs[n][k]
    #pragma unroll
    for (int i = 0; i < 8; ++i) {
      int idx = i * 256 + t;          // 0..2047
      int k = idx >> 5;               // 32 float4 per 128-col row
      int n4 = (idx & 31) << 2;
      float4 wv = *(const float4*)&Wsrc[(size_t)(kt + k) * 512 + ncol0 + n4];
      Bs[n4 + 0][k] = (short)f2bf(wv.x);
      Bs[n4 + 1][k] = (short)f2bf(wv.y);
      Bs[n4 + 2][k] = (short)f2bf(wv.z);
      Bs[n4 + 3][k] = (short)f2bf(wv.w);
    }
    __syncthreads();
    #pragma unroll
    for (int ks = 0; ks < 2; ++ks) {
      const int k0 = ks * 32 + quad * 8;
      s8v a[4], b[4];
      #pragma unroll
      for (int mi = 0; mi < 4; ++mi) a[mi] = *(const s8v*)&As[wm * 64 + mi * 16 + l16][k0];
      #pragma unroll
      for (int nj = 0; nj < 4; ++nj) b[nj] = *(const s8v*)&Bs[wn * 64 + nj * 16 + l16][k0];
      #pragma unroll
      for (int mi = 0; mi < 4; ++mi)
        #pragma unroll
        for (int nj = 0; nj < 4; ++nj)
          acc[mi][nj] = __builtin_amdgcn_mfma_f32_16x16x32_bf16(a[mi], b[nj], acc[mi][nj], 0, 0, 0);
    }
  }

  // bias (zeros in this problem, but keep semantics)
  #pragma unroll
  for (int nj = 0; nj < 4; ++nj) {
    float bias = bsrc[ncol0 + wn * 64 + nj * 16 + l16];
    #pragma unroll
    for (int mi = 0; mi < 4; ++mi) {
      acc[mi][nj][0] += bias; acc[mi][nj][1] += bias;
      acc[mi][nj][2] += bias; acc[mi][nj][3] += bias;
    }
  }

  // fused q-normalization: wave's 64 cols == one head. norm over DK=64 per row.
  if (nb < 4) {
    float g = gamma[nb * 2 + wn];
    #pragma unroll
    for (int mi = 0; mi < 4; ++mi)
      #pragma unroll
      for (int rr = 0; rr < 4; ++rr) {
        float ss = acc[mi][0][rr] * acc[mi][0][rr] + acc[mi][1][rr] * acc[mi][1][rr]
                 + acc[mi][2][rr] * acc[mi][2][rr] + acc[mi][3][rr] * acc[mi][3][rr];
        ss += __shfl_xor(ss, 1);
        ss += __shfl_xor(ss, 2);
        ss += __shfl_xor(ss, 4);
        ss += __shfl_xor(ss, 8);     // sum over the 16 lanes of this quad -> 64 cols
        float scale = g * rsqrtf(ss);
        acc[mi][0][rr] *= scale; acc[mi][1][rr] *= scale;
        acc[mi][2][rr] *= scale; acc[mi][3][rr] *= scale;
      }
  }

  // store bf16 (C/D layout: col=l16, row=quad*4+rr)
  const int colbase = nb * 128 + wn * 64;
  #pragma unroll
  for (int mi = 0; mi < 4; ++mi)
    #pragma unroll
    for (int nj = 0; nj < 4; ++nj)
      #pragma unroll
      for (int rr = 0; rr < 4; ++rr) {
        int row = row0 + wm * 64 + mi * 16 + quad * 4 + rr;
        int col = colbase + nj * 16 + l16;
        qkv[(size_t)row * 1536 + col] = f2bf(acc[mi][nj][rr]);
      }
}

// ---------------------------------------------------------------------------
// kv accumulation: kv[b,h] += K^T V over an n-chunk of 1024 rows. VALU outer
// product, fp32 atomics into kvbuf[64][64][64].
// ---------------------------------------------------------------------------
__global__ __launch_bounds__(256)
void kv_accum_kernel(const unsigned short* __restrict__ qkv, float* __restrict__ kvbuf)
{
  __shared__ short ks[16][64];
  __shared__ short vs[16][64];
  const int t = threadIdx.x;
  const int bh = blockIdx.x, chunk = blockIdx.y;
  const int b = bh >> 3, h = bh & 7;
  const int base_row = b * 8192 + chunk * 1024;
  const int dk0 = (t >> 4) << 2;
  const int dv0 = (t & 15) << 2;
  float acc[4][4] = {};

  for (int it = 0; it < 64; ++it) {
    __syncthreads();
    {
      int half = t >> 7;            // 0: stage k, 1: stage v
      int tt = t & 127;
      int r = tt >> 3, u = tt & 7;
      int col = (half ? 1024 : 512) + h * 64 + u * 8;
      int4 raw = *(const int4*)&qkv[(size_t)(base_row + it * 16 + r) * 1536 + col];
      if (half == 0) *(int4*)&ks[r][u * 8] = raw;
      else           *(int4*)&vs[r][u * 8] = raw;
    }
    __syncthreads();
    #pragma unroll
    for (int rr = 0; rr < 16; ++rr) {
      s4v kk = *(const s4v*)&ks[rr][dk0];
      s4v vv = *(const s4v*)&vs[rr][dv0];
      float kf[4], vf[4];
      #pragma unroll
      for (int i = 0; i < 4; ++i) { kf[i] = bf2f((unsigned short)kk[i]); vf[i] = bf2f((unsigned short)vv[i]); }
      #pragma unroll
      for (int i = 0; i < 4; ++i)
        #pragma unroll
        for (int j = 0; j < 4; ++j)
          acc[i][j] = fmaf(kf[i], vf[j], acc[i][j]);
    }
  }
  float* dst = kvbuf + (size_t)bh * 4096;
  #pragma unroll
  for (int i = 0; i < 4; ++i)
    #pragma unroll
    for (int j = 0; j < 4; ++j)
      atomicAdd(&dst[(dk0 + i) * 64 + dv0 + j], acc[i][j]);
}

// ---------------------------------------------------------------------------
// kv normalize: mkv = kv * gamma[h] / ||row over DV||
// ---------------------------------------------------------------------------
__global__ __launch_bounds__(256)
void kv_norm_kernel(const float* __restrict__ kvbuf, const float* __restrict__ gamma,
                    float* __restrict__ mkv)
{
  const int bh = blockIdx.x, h = bh & 7;
  const int t = threadIdx.x;
  const int row = t >> 2, qq = t & 3;
  const float* src = kvbuf + (size_t)bh * 4096 + row * 64 + qq * 16;
  float v[16]; float ss = 0.f;
  #pragma unroll
  for (int i = 0; i < 16; ++i) { v[i] = src[i]; ss += v[i] * v[i]; }
  ss += __shfl_xor(ss, 1);
  ss += __shfl_xor(ss, 2);      // sum over the 4 lanes covering this row
  float scale = gamma[h] * rsqrtf(ss);
  float* dst = mkv + (size_t)bh * 4096 + row * 64 + qq * 16;
  #pragma unroll
  for (int i = 0; i < 16; ++i) dst[i] = v[i] * scale;
}

// ---------------------------------------------------------------------------
// W2[b][(h,k)][d] = sum_v mkv[b,h][k][v] * Wo[h*64+v][d]   (bf16 out)
// grid (8, 32): each block does all 512 rows x 16 d-cols.
// ---------------------------------------------------------------------------
__global__ __launch_bounds__(256)
void build_w2_kernel(const float* __restrict__ mkv, const float* __restrict__ Wo,
                     unsigned short* __restrict__ W2)
{
  __shared__ float WoS[512][16];
  const int b = blockIdx.x, dt = blockIdx.y;
  const int d0 = dt * 16;
  const int t = threadIdx.x;
  for (int i = 0; i < 32; ++i) {
    int flat = i * 256 + t;
    int r = flat >> 4, c = flat & 15;
    WoS[r][c] = Wo[(size_t)r * 512 + d0 + c];
  }
  __syncthreads();
  for (int rr = 0; rr < 2; ++rr) {
    int r = rr * 256 + t;
    int h = r >> 6, k = r & 63;
    const float* mrow = mkv + (size_t)(b * 8 + h) * 4096 + k * 64;
    float accv[16] = {};
    for (int v = 0; v < 64; ++v) {
      float m = mrow[v];
      const float* w = &WoS[h * 64 + v][0];
      #pragma unroll
      for (int j = 0; j < 16; ++j) accv[j] = fmaf(m, w[j], accv[j]);
    }
    unsigned short* dst = W2 + ((size_t)b * 512 + r) * 512 + d0;
    #pragma unroll
    for (int j = 0; j < 16; ++j) dst[j] = f2bf(accv[j]);
  }
}

// ---------------------------------------------------------------------------
// GEMM3: Y[b] = qhat[b] @ W2[b] + bo, fp32 out. Same tile structure as GEMM1.
// A = qkv cols 0..511 (lda 1536, bf16). B = W2 per batch (b = rowblock/64).
// ---------------------------------------------------------------------------
__global__ __launch_bounds__(256, 2)
void gemm_out_kernel(const unsigned short* __restrict__ qkv,
                     const unsigned short* __restrict__ W2,
                     const float* __restrict__ bo,
                     float* __restrict__ out)
{
  __shared__ short As[128][72];
  __shared__ short Bs[128][72];
  const int t = threadIdx.x;
  const int rb = blockIdx.x, nb = blockIdx.y;
  const int wave = t >> 6, lane = t & 63;
  const int wm = wave & 1, wn = wave >> 1;
  const int quad = lane >> 4, l16 = lane & 15;
  const int row0 = rb * 128;
  const int ncol0 = nb * 128;
  const unsigned short* Wb = W2 + (size_t)(rb >> 6) * 512 * 512;

  f4v acc[4][4];
  #pragma unroll
  for (int i = 0; i < 4; ++i)
    #pragma unroll
    for (int j = 0; j < 4; ++j) acc[i][j] = (f4v){0.f, 0.f, 0.f, 0.f};

  for (int kt = 0; kt < 512; kt += 64) {
    __syncthreads();
    // stage A: 128x64 bf16, direct 16B copies
    #pragma unroll
    for (int i = 0; i < 4; ++i) {
      int idx = i * 256 + t;          // 0..1023
      int m = idx >> 3;               // 8 x (8 bf16) per row
      int k8 = (idx & 7) << 3;
      int4 raw = *(const int4*)&qkv[(size_t)(row0 + m) * 1536 + kt + k8];
      *(int4*)&As[m][k8] = raw;
    }
    // stage B: 64x128 bf16, transposed
    #pragma unroll
    for (int i = 0; i < 4; ++i) {
      int idx = i * 256 + t;          // 0..1023
      int k = idx >> 4;               // 16 x (8 bf16) per row
      int n8 = (idx & 15) << 3;
      union { int4 v; short s[8]; } u;
      u.v = *(const int4*)&Wb[(size_t)(kt + k) * 512 + ncol0 + n8];
      #pragma unroll
      for (int p = 0; p < 8; ++p) Bs[n8 + p][k] = u.s[p];
    }
    __syncthreads();
    #pragma unroll
    for (int ks = 0; ks < 2; ++ks) {
      const int k0 = ks * 32 + quad * 8;
      s8v a[4], b[4];
      #pragma unroll
      for (int mi = 0; mi < 4; ++mi) a[mi] = *(const s8v*)&As[wm * 64 + mi * 16 + l16][k0];
      #pragma unroll
      for (int nj = 0; nj < 4; ++nj) b[nj] = *(const s8v*)&Bs[wn * 64 + nj * 16 + l16][k0];
      #pragma unroll
      for (int mi = 0; mi < 4; ++mi)
        #pragma unroll
        for (int nj = 0; nj < 4; ++nj)
          acc[mi][nj] = __builtin_amdgcn_mfma_f32_16x16x32_bf16(a[mi], b[nj], acc[mi][nj], 0, 0, 0);
    }
  }

  const int colbase = ncol0 + wn * 64;
  #pragma unroll
  for (int nj = 0; nj < 4; ++nj) {
    float bias = bo[colbase + nj * 16 + l16];
    #pragma unroll
    for (int mi = 0; mi < 4; ++mi)
      #pragma unroll
      for (int rr = 0; rr < 4; ++rr) {
        int row = row0 + wm * 64 + mi * 16 + quad * 4 + rr;
        int col = colbase + nj * 16 + l16;
        out[(size_t)row * 512 + col] = acc[mi][nj][rr] + bias;
      }
  }
}

// ---------------------------------------------------------------------------
extern "C" void kernel_launch(void* const* d_in, const int* in_sizes, int n_in,
                              void* d_out, int out_size, void* d_ws, size_t ws_size,
                              hipStream_t stream)
{
  (void)in_sizes; (void)n_in; (void)out_size; (void)ws_size;
  const float* X     = (const float*)d_in[0];
  const float* Wq    = (const float*)d_in[1];
  const float* bq    = (const float*)d_in[2];
  const float* Wk    = (const float*)d_in[3];
  const float* bk    = (const float*)d_in[4];
  const float* Wv    = (const float*)d_in[5];
  const float* bv    = (const float*)d_in[6];
  const float* Wo    = (const float*)d_in[7];
  const float* bo    = (const float*)d_in[8];
  const float* gamma = (const float*)d_in[9];

  char* ws = (char*)d_ws;
  unsigned short* qkv = (unsigned short*)ws;                      // 65536*1536*2 = 201326592 B
  float* kvbuf = (float*)(ws + 201326592);                        // 64*64*64*4   = 1 MiB
  float* mkv   = kvbuf + 64 * 4096;                               // 1 MiB
  unsigned short* W2 = (unsigned short*)(mkv + 64 * 4096);        // 8*512*512*2  = 4 MiB

  hipMemsetAsync(kvbuf, 0, 64 * 4096 * sizeof(float), stream);

  dim3 blk(256);
  gemm_qkv_kernel<<<dim3(512, 12), blk, 0, stream>>>(X, Wq, bq, Wk, bk, Wv, bv, gamma, qkv);
  kv_accum_kernel<<<dim3(64, 8), blk, 0, stream>>>(qkv, kvbuf);
  kv_norm_kernel<<<dim3(64), blk, 0, stream>>>(kvbuf, gamma, mkv);
  build_w2_kernel<<<dim3(8, 32), blk, 0, stream>>>(mkv, Wo, W2);
  gemm_out_kernel<<<dim3(512, 4), blk, 0, stream>>>(qkv, W2, bo, (float*)d_out);
}

// Round 2
// 653.380 us; speedup vs baseline: 1.5015x; 1.5015x over previous
//
#include <hip/hip_runtime.h>

typedef __attribute__((ext_vector_type(8))) short s8v;
typedef __attribute__((ext_vector_type(4))) short s4v;
typedef __attribute__((ext_vector_type(4))) float f4v;

__device__ __forceinline__ unsigned short f2bf(float f) {
  unsigned int u = __float_as_uint(f);
  u += 0x7FFFu + ((u >> 16) & 1u);   // RNE
  return (unsigned short)(u >> 16);
}
__device__ __forceinline__ float bf2f(unsigned short s) {
  return __uint_as_float(((unsigned int)s) << 16);
}

// async global->LDS 16B: lane i deposits at lds_base + i*16 (wave-uniform base)
__device__ __forceinline__ void gld16(const void* g, void* l) {
  __builtin_amdgcn_global_load_lds(
      (const __attribute__((address_space(1))) unsigned int*)g,
      (__attribute__((address_space(3))) unsigned int*)l, 16, 0, 0);
}

// ---------------------------------------------------------------------------
// Pass 0a: X fp32 [65536,512] -> Xbf bf16. 16384 blocks x 256 thr x 8 elems.
// ---------------------------------------------------------------------------
__global__ __launch_bounds__(256)
void convert_x_kernel(const float* __restrict__ X, unsigned short* __restrict__ Xbf)
{
  size_t base = ((size_t)blockIdx.x * 256 + threadIdx.x) * 8;
  float4 a = *(const float4*)&X[base];
  float4 b = *(const float4*)&X[base + 4];
  s8v p = (s8v){ (short)f2bf(a.x), (short)f2bf(a.y), (short)f2bf(a.z), (short)f2bf(a.w),
                 (short)f2bf(b.x), (short)f2bf(b.y), (short)f2bf(b.z), (short)f2bf(b.w) };
  *(s8v*)&Xbf[base] = p;
}

// ---------------------------------------------------------------------------
// Pass 0b: Wt[n][k] bf16, n = 0..511 Wq | 512..1023 Wk | 1024..1535 Wv.
// grid (8 k-tiles, 24 n-tiles), 64x64 tile transpose through LDS.
// ---------------------------------------------------------------------------
__global__ __launch_bounds__(256)
void transpose_w_kernel(const float* __restrict__ Wq, const float* __restrict__ Wk,
                        const float* __restrict__ Wv, unsigned short* __restrict__ Wt)
{
  __shared__ float T[64][68];
  const int kt = blockIdx.x, nt = blockIdx.y;
  const float* W = (nt < 8) ? Wq : (nt < 16 ? Wk : Wv);
  const int n0 = (nt & 7) * 64, k0 = kt * 64;
  const int t = threadIdx.x;
  #pragma unroll
  for (int it = 0; it < 4; ++it) {
    int idx = it * 256 + t;
    int k = idx >> 4, n4 = (idx & 15) << 2;
    *(float4*)&T[k][n4] = *(const float4*)&W[(size_t)(k0 + k) * 512 + n0 + n4];
  }
  __syncthreads();
  #pragma unroll
  for (int it = 0; it < 2; ++it) {
    int idx = it * 256 + t;
    int n = idx >> 3, k8 = (idx & 7) << 3;
    s8v p;
    #pragma unroll
    for (int j = 0; j < 8; ++j) p[j] = (short)f2bf(T[k8 + j][n]);
    *(s8v*)&Wt[((size_t)nt * 64 + n) * 512 + k0 + k8] = p;
  }
}

// ---------------------------------------------------------------------------
// GEMM1: qkv = Xbf @ Wt^T (+bias), q-part normalized per head * gamma.
// m97 structure: global_load_lds x16B, granule LDS layout, ds_read_b128.
// LDS granule (m,kb) at (kb*128+m)*16B; tile 128x128, BK=64, 4 waves.
// ---------------------------------------------------------------------------
__global__ __launch_bounds__(256, 2)
void gemm_qkv_kernel(const unsigned short* __restrict__ Xbf,
                     const unsigned short* __restrict__ Wt,
                     const float* __restrict__ bq, const float* __restrict__ bk,
                     const float* __restrict__ bv,
                     const float* __restrict__ gamma,
                     unsigned short* __restrict__ qkv)
{
  __shared__ short As[8192];   // 8 kb * 128 m * 8 shorts = 16 KB
  __shared__ short Bs[8192];
  const int t = threadIdx.x;
  const int rb = blockIdx.x, nb = blockIdx.y;
  const int wave = t >> 6, lane = t & 63;
  const int wm = wave & 1, wn = wave >> 1;
  const int quad = lane >> 4, l16 = lane & 15;
  const int row0 = rb * 128;
  const int ncol0 = nb * 128;                 // 0..1535

  const unsigned short* Abase = Xbf + (size_t)(row0 + lane) * 512;
  const unsigned short* Bbase = Wt + (size_t)(ncol0 + lane) * 512;

  f4v acc[4][4];
  #pragma unroll
  for (int i = 0; i < 4; ++i)
    #pragma unroll
    for (int j = 0; j < 4; ++j) acc[i][j] = (f4v){0.f, 0.f, 0.f, 0.f};

  for (int kt = 0; kt < 512; kt += 64) {
    __syncthreads();
    #pragma unroll
    for (int i = 0; i < 4; ++i) {
      const int moff = (i & 1) * 64;
      const int kb = wave * 2 + (i >> 1);
      gld16(Abase + (size_t)moff * 512 + kt + kb * 8, &As[(wave * 256 + i * 64) * 8]);
      gld16(Bbase + (size_t)moff * 512 + kt + kb * 8, &Bs[(wave * 256 + i * 64) * 8]);
    }
    __syncthreads();   // compiler emits s_waitcnt vmcnt(0) before s_barrier
    #pragma unroll
    for (int ks = 0; ks < 2; ++ks) {
      const int kb = ks * 4 + quad;
      s8v a[4], b[4];
      #pragma unroll
      for (int mi = 0; mi < 4; ++mi)
        a[mi] = *(const s8v*)&As[(kb * 128 + wm * 64 + mi * 16 + l16) * 8];
      #pragma unroll
      for (int nj = 0; nj < 4; ++nj)
        b[nj] = *(const s8v*)&Bs[(kb * 128 + wn * 64 + nj * 16 + l16) * 8];
      #pragma unroll
      for (int mi = 0; mi < 4; ++mi)
        #pragma unroll
        for (int nj = 0; nj < 4; ++nj)
          acc[mi][nj] = __builtin_amdgcn_mfma_f32_16x16x32_bf16(a[mi], b[nj], acc[mi][nj], 0, 0, 0);
    }
  }

  // bias (zeros in this problem, kept for semantics)
  #pragma unroll
  for (int nj = 0; nj < 4; ++nj) {
    int colg = ncol0 + wn * 64 + nj * 16 + l16;
    float bias;
    if (colg < 512) bias = bq[colg];
    else if (colg < 1024) bias = bk[colg - 512];
    else bias = bv[colg - 1024];
    #pragma unroll
    for (int mi = 0; mi < 4; ++mi) {
      acc[mi][nj][0] += bias; acc[mi][nj][1] += bias;
      acc[mi][nj][2] += bias; acc[mi][nj][3] += bias;
    }
  }

  // fused q-normalization: wave's 64 cols == one head; norm over DK=64 per row
  if (nb < 4) {
    float g = gamma[nb * 2 + wn];
    #pragma unroll
    for (int mi = 0; mi < 4; ++mi)
      #pragma unroll
      for (int rr = 0; rr < 4; ++rr) {
        float ss = acc[mi][0][rr] * acc[mi][0][rr] + acc[mi][1][rr] * acc[mi][1][rr]
                 + acc[mi][2][rr] * acc[mi][2][rr] + acc[mi][3][rr] * acc[mi][3][rr];
        ss += __shfl_xor(ss, 1);
        ss += __shfl_xor(ss, 2);
        ss += __shfl_xor(ss, 4);
        ss += __shfl_xor(ss, 8);
        float scale = g * rsqrtf(ss);
        acc[mi][0][rr] *= scale; acc[mi][1][rr] *= scale;
        acc[mi][2][rr] *= scale; acc[mi][3][rr] *= scale;
      }
  }

  const int colbase = ncol0 + wn * 64;
  #pragma unroll
  for (int mi = 0; mi < 4; ++mi)
    #pragma unroll
    for (int nj = 0; nj < 4; ++nj)
      #pragma unroll
      for (int rr = 0; rr < 4; ++rr) {
        int row = row0 + wm * 64 + mi * 16 + quad * 4 + rr;
        int col = colbase + nj * 16 + l16;
        qkv[(size_t)row * 1536 + col] = f2bf(acc[mi][nj][rr]);
      }
}

// ---------------------------------------------------------------------------
// kv partials: per (bh, chunk of 512 rows) compute K^T V, fp32 LDS staging
// (convert once per stage, inner loop pure FMA). Partials, no atomics.
// ---------------------------------------------------------------------------
__global__ __launch_bounds__(256)
void kv_accum_kernel(const unsigned short* __restrict__ qkv, float* __restrict__ kvpart)
{
  __shared__ float ksf[16][64];
  __shared__ float vsf[16][64];
  const int t = threadIdx.x;
  const int bh = blockIdx.x, chunk = blockIdx.y;   // (64, 16)
  const int b = bh >> 3, h = bh & 7;
  const int base_row = b * 8192 + chunk * 512;
  const int dk0 = (t >> 4) << 2, dv0 = (t & 15) << 2;
  const int half = t >> 7, tt = t & 127;
  const int r = tt >> 3, u = tt & 7;
  const int col = (half ? 1024 : 512) + h * 64 + u * 8;
  const unsigned short* src = qkv + (size_t)(base_row + r) * 1536 + col;
  float* dstlds = half ? &vsf[r][u * 8] : &ksf[r][u * 8];
  float acc[4][4] = {};

  for (int it = 0; it < 32; ++it) {
    __syncthreads();
    union { int4 v; unsigned short s[8]; } raw;
    raw.v = *(const int4*)(src + (size_t)it * 16 * 1536);
    float4 lo = { bf2f(raw.s[0]), bf2f(raw.s[1]), bf2f(raw.s[2]), bf2f(raw.s[3]) };
    float4 hi = { bf2f(raw.s[4]), bf2f(raw.s[5]), bf2f(raw.s[6]), bf2f(raw.s[7]) };
    *(float4*)dstlds = lo;
    *(float4*)(dstlds + 4) = hi;
    __syncthreads();
    #pragma unroll
    for (int rr = 0; rr < 16; ++rr) {
      float4 kk = *(const float4*)&ksf[rr][dk0];
      float4 vv = *(const float4*)&vsf[rr][dv0];
      float kf[4] = { kk.x, kk.y, kk.z, kk.w };
      float vf[4] = { vv.x, vv.y, vv.z, vv.w };
      #pragma unroll
      for (int i = 0; i < 4; ++i)
        #pragma unroll
        for (int j = 0; j < 4; ++j)
          acc[i][j] = fmaf(kf[i], vf[j], acc[i][j]);
    }
  }
  float* dst = kvpart + ((size_t)chunk * 64 + bh) * 4096;
  #pragma unroll
  for (int i = 0; i < 4; ++i)
    *(float4*)&dst[(dk0 + i) * 64 + dv0] = (float4){ acc[i][0], acc[i][1], acc[i][2], acc[i][3] };
}

// ---------------------------------------------------------------------------
// reduce 16 chunk partials -> kvbuf[bh][4096]
// ---------------------------------------------------------------------------
__global__ __launch_bounds__(256)
void kv_reduce_kernel(const float* __restrict__ kvpart, float* __restrict__ kvbuf)
{
  const int bh = blockIdx.x, t = threadIdx.x;
  #pragma unroll
  for (int e = 0; e < 16; ++e) {
    int i = e * 256 + t;
    float s = 0.f;
    #pragma unroll
    for (int c = 0; c < 16; ++c) s += kvpart[((size_t)c * 64 + bh) * 4096 + i];
    kvbuf[(size_t)bh * 4096 + i] = s;
  }
}

// ---------------------------------------------------------------------------
// W2t[b][d][(h,k)] = sum_v (kv[b,h][k][v]*gamma[h]/||kv row||) * Wo[h*64+v][d]
// Transposed output -> GEMM3 B staging is a straight 16B copy. Norm inlined.
// grid (8 b, 32 d-tiles of 16).
// ---------------------------------------------------------------------------
__global__ __launch_bounds__(256)
void build_w2t_kernel(const float* __restrict__ kvbuf, const float* __restrict__ Wo,
                      const float* __restrict__ gamma, unsigned short* __restrict__ W2t)
{
  __shared__ float WoS[512][16];
  const int b = blockIdx.x, dt = blockIdx.y;
  const int d0 = dt * 16;
  const int t = threadIdx.x;
  for (int i = 0; i < 32; ++i) {
    int flat = i * 256 + t;
    int rr_ = flat >> 4, c = flat & 15;
    WoS[rr_][c] = Wo[(size_t)rr_ * 512 + d0 + c];
  }
  __syncthreads();
  for (int rr = 0; rr < 2; ++rr) {
    int r = rr * 256 + t;
    int h = r >> 6, k = r & 63;
    const float* krow = kvbuf + ((size_t)b * 8 + h) * 4096 + (size_t)k * 64;
    float ss = 0.f;
    #pragma unroll
    for (int v = 0; v < 64; v += 4) {
      float4 x = *(const float4*)&krow[v];
      ss += x.x * x.x + x.y * x.y + x.z * x.z + x.w * x.w;
    }
    float scale = gamma[h] * rsqrtf(ss);
    f4v accv[4];
    #pragma unroll
    for (int j = 0; j < 4; ++j) accv[j] = (f4v){0.f, 0.f, 0.f, 0.f};
    for (int v = 0; v < 64; ++v) {
      float m = krow[v] * scale;
      const float* w = &WoS[h * 64 + v][0];
      #pragma unroll
      for (int j4 = 0; j4 < 4; ++j4) {
        float4 ww = *(const float4*)&w[j4 * 4];
        accv[j4][0] = fmaf(m, ww.x, accv[j4][0]);
        accv[j4][1] = fmaf(m, ww.y, accv[j4][1]);
        accv[j4][2] = fmaf(m, ww.z, accv[j4][2]);
        accv[j4][3] = fmaf(m, ww.w, accv[j4][3]);
      }
    }
    #pragma unroll
    for (int j = 0; j < 16; ++j)
      W2t[((size_t)b * 512 + d0 + j) * 512 + r] = f2bf(accv[j >> 2][j & 3]);
  }
}

// ---------------------------------------------------------------------------
// GEMM3: Y[b] = qhat[b] @ W2[b] + bo, fp32 out. Same m97 structure.
// A = qkv cols 0..511 (lda 1536). B = W2t (already [n][k]).
// ---------------------------------------------------------------------------
__global__ __launch_bounds__(256, 2)
void gemm_out_kernel(const unsigned short* __restrict__ qkv,
                     const unsigned short* __restrict__ W2t,
                     const float* __restrict__ bo,
                     float* __restrict__ out)
{
  __shared__ short As[8192];
  __shared__ short Bs[8192];
  const int t = threadIdx.x;
  const int rb = blockIdx.x, nb = blockIdx.y;
  const int wave = t >> 6, lane = t & 63;
  const int wm = wave & 1, wn = wave >> 1;
  const int quad = lane >> 4, l16 = lane & 15;
  const int row0 = rb * 128;
  const int ncol0 = nb * 128;

  const unsigned short* Abase = qkv + (size_t)(row0 + lane) * 1536;
  const unsigned short* Bbase = W2t + (size_t)(rb >> 6) * 262144 + (size_t)(ncol0 + lane) * 512;

  f4v acc[4][4];
  #pragma unroll
  for (int i = 0; i < 4; ++i)
    #pragma unroll
    for (int j = 0; j < 4; ++j) acc[i][j] = (f4v){0.f, 0.f, 0.f, 0.f};

  for (int kt = 0; kt < 512; kt += 64) {
    __syncthreads();
    #pragma unroll
    for (int i = 0; i < 4; ++i) {
      const int moff = (i & 1) * 64;
      const int kb = wave * 2 + (i >> 1);
      gld16(Abase + (size_t)moff * 1536 + kt + kb * 8, &As[(wave * 256 + i * 64) * 8]);
      gld16(Bbase + (size_t)moff * 512 + kt + kb * 8, &Bs[(wave * 256 + i * 64) * 8]);
    }
    __syncthreads();
    #pragma unroll
    for (int ks = 0; ks < 2; ++ks) {
      const int kb = ks * 4 + quad;
      s8v a[4], b[4];
      #pragma unroll
      for (int mi = 0; mi < 4; ++mi)
        a[mi] = *(const s8v*)&As[(kb * 128 + wm * 64 + mi * 16 + l16) * 8];
      #pragma unroll
      for (int nj = 0; nj < 4; ++nj)
        b[nj] = *(const s8v*)&Bs[(kb * 128 + wn * 64 + nj * 16 + l16) * 8];
      #pragma unroll
      for (int mi = 0; mi < 4; ++mi)
        #pragma unroll
        for (int nj = 0; nj < 4; ++nj)
          acc[mi][nj] = __builtin_amdgcn_mfma_f32_16x16x32_bf16(a[mi], b[nj], acc[mi][nj], 0, 0, 0);
    }
  }

  const int colbase = ncol0 + wn * 64;
  #pragma unroll
  for (int nj = 0; nj < 4; ++nj) {
    float bias = bo[colbase + nj * 16 + l16];
    #pragma unroll
    for (int mi = 0; mi < 4; ++mi)
      #pragma unroll
      for (int rr = 0; rr < 4; ++rr) {
        int row = row0 + wm * 64 + mi * 16 + quad * 4 + rr;
        int col = colbase + nj * 16 + l16;
        out[(size_t)row * 512 + col] = acc[mi][nj][rr] + bias;
      }
  }
}

// ---------------------------------------------------------------------------
extern "C" void kernel_launch(void* const* d_in, const int* in_sizes, int n_in,
                              void* d_out, int out_size, void* d_ws, size_t ws_size,
                              hipStream_t stream)
{
  (void)in_sizes; (void)n_in; (void)out_size; (void)ws_size;
  const float* X     = (const float*)d_in[0];
  const float* Wq    = (const float*)d_in[1];
  const float* bq    = (const float*)d_in[2];
  const float* Wk    = (const float*)d_in[3];
  const float* bk    = (const float*)d_in[4];
  const float* Wv    = (const float*)d_in[5];
  const float* bv    = (const float*)d_in[6];
  const float* Wo    = (const float*)d_in[7];
  const float* bo    = (const float*)d_in[8];
  const float* gamma = (const float*)d_in[9];

  char* ws = (char*)d_ws;
  unsigned short* qkv = (unsigned short*)ws;                         // 201326592 B
  unsigned short* Xbf = (unsigned short*)(ws + 201326592);           // 67108864 B
  float* kvpart = (float*)(ws + 201326592);                          // aliases Xbf (dead after gemm1): 16777216 B
  unsigned short* Wt  = (unsigned short*)(ws + 201326592 + 67108864);          // 1572864 B
  float* kvbuf        = (float*)(ws + 201326592 + 67108864 + 1572864);         // 1048576 B
  unsigned short* W2t = (unsigned short*)(ws + 201326592 + 67108864 + 1572864 + 1048576); // 4194304 B

  dim3 blk(256);
  convert_x_kernel<<<16384, blk, 0, stream>>>(X, Xbf);
  transpose_w_kernel<<<dim3(8, 24), blk, 0, stream>>>(Wq, Wk, Wv, Wt);
  gemm_qkv_kernel<<<dim3(512, 12), blk, 0, stream>>>(Xbf, Wt, bq, bk, bv, gamma, qkv);
  kv_accum_kernel<<<dim3(64, 16), blk, 0, stream>>>(qkv, kvpart);
  kv_reduce_kernel<<<64, blk, 0, stream>>>(kvpart, kvbuf);
  build_w2t_kernel<<<dim3(8, 32), blk, 0, stream>>>(kvbuf, Wo, gamma, W2t);
  gemm_out_kernel<<<dim3(512, 4), blk, 0, stream>>>(qkv, W2t, bo, (float*)d_out);
}

// Round 3
// 576.006 us; speedup vs baseline: 1.7032x; 1.1343x over previous
//
#include <hip/hip_runtime.h>

typedef __attribute__((ext_vector_type(8))) short s8v;
typedef __attribute__((ext_vector_type(4))) short s4v;
typedef __attribute__((ext_vector_type(4))) float f4v;

__device__ __forceinline__ unsigned short f2bf(float f) {
  unsigned int u = __float_as_uint(f);
  u += 0x7FFFu + ((u >> 16) & 1u);   // RNE
  return (unsigned short)(u >> 16);
}
__device__ __forceinline__ float bf2f(unsigned short s) {
  return __uint_as_float(((unsigned int)s) << 16);
}

// async global->LDS 16B: lane i deposits at wave-uniform base + i*16
__device__ __forceinline__ void gld16(const void* g, void* l) {
  __builtin_amdgcn_global_load_lds(
      (const __attribute__((address_space(1))) unsigned int*)g,
      (__attribute__((address_space(3))) unsigned int*)l, 16, 0, 0);
}

// ---------------------------------------------------------------------------
// Pass 0a: X fp32 [65536,512] -> Xbf bf16.
// ---------------------------------------------------------------------------
__global__ __launch_bounds__(256)
void convert_x_kernel(const float* __restrict__ X, unsigned short* __restrict__ Xbf)
{
  size_t base = ((size_t)blockIdx.x * 256 + threadIdx.x) * 8;
  float4 a = *(const float4*)&X[base];
  float4 b = *(const float4*)&X[base + 4];
  s8v p = (s8v){ (short)f2bf(a.x), (short)f2bf(a.y), (short)f2bf(a.z), (short)f2bf(a.w),
                 (short)f2bf(b.x), (short)f2bf(b.y), (short)f2bf(b.z), (short)f2bf(b.w) };
  *(s8v*)&Xbf[base] = p;
}

// ---------------------------------------------------------------------------
// Pass 0b: Wt[n][k] bf16, n = 0..511 Wq | 512..1023 Wk | 1024..1535 Wv.
// ---------------------------------------------------------------------------
__global__ __launch_bounds__(256)
void transpose_w_kernel(const float* __restrict__ Wq, const float* __restrict__ Wk,
                        const float* __restrict__ Wv, unsigned short* __restrict__ Wt)
{
  __shared__ float T[64][68];
  const int kt = blockIdx.x, nt = blockIdx.y;
  const float* W = (nt < 8) ? Wq : (nt < 16 ? Wk : Wv);
  const int n0 = (nt & 7) * 64, k0 = kt * 64;
  const int t = threadIdx.x;
  #pragma unroll
  for (int it = 0; it < 4; ++it) {
    int idx = it * 256 + t;
    int k = idx >> 4, n4 = (idx & 15) << 2;
    *(float4*)&T[k][n4] = *(const float4*)&W[(size_t)(k0 + k) * 512 + n0 + n4];
  }
  __syncthreads();
  #pragma unroll
  for (int it = 0; it < 2; ++it) {
    int idx = it * 256 + t;
    int n = idx >> 3, k8 = (idx & 7) << 3;
    s8v p;
    #pragma unroll
    for (int j = 0; j < 8; ++j) p[j] = (short)f2bf(T[k8 + j][n]);
    *(s8v*)&Wt[((size_t)nt * 64 + n) * 512 + k0 + k8] = p;
  }
}

// ---------------------------------------------------------------------------
// GEMM1: qkv = Xbf @ Wt^T (+bias), q-part normalized per head * gamma.
// XOR-swizzled coalesced global_load_lds staging:
//   LDS slot s holds global granule (m = s>>3, kb = (s&7)^(m&7)).
//   Wave-inst reads 8 rows x 128B windows (16 lines) instead of 64 scattered.
// grid (12 nb, 512 rb) -- nb fast for A-tile L2 reuse.
// ---------------------------------------------------------------------------
__global__ __launch_bounds__(256, 2)
void gemm_qkv_kernel(const unsigned short* __restrict__ Xbf,
                     const unsigned short* __restrict__ Wt,
                     const float* __restrict__ bq, const float* __restrict__ bk,
                     const float* __restrict__ bv,
                     const float* __restrict__ gamma,
                     unsigned short* __restrict__ qkv)
{
  __shared__ short As[8192];   // 1024 granules x 16B = 16 KB
  __shared__ short Bs[8192];
  const int t = threadIdx.x;
  const int nb = blockIdx.x, rb = blockIdx.y;
  const int wave = t >> 6, lane = t & 63;
  const int wm = wave & 1, wn = wave >> 1;
  const int quad = lane >> 4, l16 = lane & 15;
  const int row0 = rb * 128;
  const int ncol0 = nb * 128;

  // staging pointers: 4 granule slots per thread for each of A,B
  const unsigned short* ap[4];
  const unsigned short* bp[4];
  #pragma unroll
  for (int i = 0; i < 4; ++i) {
    int s = i * 256 + t;
    int m = s >> 3;
    int kb = (s & 7) ^ (m & 7);
    ap[i] = Xbf + (size_t)(row0 + m) * 512 + kb * 8;
    bp[i] = Wt + (size_t)(ncol0 + m) * 512 + kb * 8;
  }

  f4v acc[4][4];
  #pragma unroll
  for (int i = 0; i < 4; ++i)
    #pragma unroll
    for (int j = 0; j < 4; ++j) acc[i][j] = (f4v){0.f, 0.f, 0.f, 0.f};

  for (int kt = 0; kt < 512; kt += 64) {
    __syncthreads();
    #pragma unroll
    for (int i = 0; i < 4; ++i) {
      int s8 = (i * 256 + t) * 8;
      gld16(ap[i] + kt, &As[s8]);
      gld16(bp[i] + kt, &Bs[s8]);
    }
    __syncthreads();
    #pragma unroll
    for (int ks = 0; ks < 2; ++ks) {
      s8v a[4], b[4];
      #pragma unroll
      for (int mi = 0; mi < 4; ++mi) {
        int r = wm * 64 + mi * 16 + l16;
        int slot = r * 8 + ((ks * 4 + quad) ^ (r & 7));
        a[mi] = *(const s8v*)&As[slot * 8];
      }
      #pragma unroll
      for (int nj = 0; nj < 4; ++nj) {
        int r = wn * 64 + nj * 16 + l16;
        int slot = r * 8 + ((ks * 4 + quad) ^ (r & 7));
        b[nj] = *(const s8v*)&Bs[slot * 8];
      }
      #pragma unroll
      for (int mi = 0; mi < 4; ++mi)
        #pragma unroll
        for (int nj = 0; nj < 4; ++nj)
          acc[mi][nj] = __builtin_amdgcn_mfma_f32_16x16x32_bf16(a[mi], b[nj], acc[mi][nj], 0, 0, 0);
    }
  }

  // bias (zeros here, kept for semantics)
  #pragma unroll
  for (int nj = 0; nj < 4; ++nj) {
    int colg = ncol0 + wn * 64 + nj * 16 + l16;
    float bias;
    if (colg < 512) bias = bq[colg];
    else if (colg < 1024) bias = bk[colg - 512];
    else bias = bv[colg - 1024];
    #pragma unroll
    for (int mi = 0; mi < 4; ++mi) {
      acc[mi][nj][0] += bias; acc[mi][nj][1] += bias;
      acc[mi][nj][2] += bias; acc[mi][nj][3] += bias;
    }
  }

  // fused q-normalization: wave's 64 cols == one head; norm over DK=64 per row
  if (nb < 4) {
    float g = gamma[nb * 2 + wn];
    #pragma unroll
    for (int mi = 0; mi < 4; ++mi)
      #pragma unroll
      for (int rr = 0; rr < 4; ++rr) {
        float ss = acc[mi][0][rr] * acc[mi][0][rr] + acc[mi][1][rr] * acc[mi][1][rr]
                 + acc[mi][2][rr] * acc[mi][2][rr] + acc[mi][3][rr] * acc[mi][3][rr];
        ss += __shfl_xor(ss, 1);
        ss += __shfl_xor(ss, 2);
        ss += __shfl_xor(ss, 4);
        ss += __shfl_xor(ss, 8);
        float scale = g * rsqrtf(ss);
        acc[mi][0][rr] *= scale; acc[mi][1][rr] *= scale;
        acc[mi][2][rr] *= scale; acc[mi][3][rr] *= scale;
      }
  }

  const int colbase = ncol0 + wn * 64;
  #pragma unroll
  for (int mi = 0; mi < 4; ++mi)
    #pragma unroll
    for (int nj = 0; nj < 4; ++nj)
      #pragma unroll
      for (int rr = 0; rr < 4; ++rr) {
        int row = row0 + wm * 64 + mi * 16 + quad * 4 + rr;
        int col = colbase + nj * 16 + l16;
        qkv[(size_t)row * 1536 + col] = f2bf(acc[mi][nj][rr]);
      }
}

// ---------------------------------------------------------------------------
// kv partials: per (bh, chunk of 512 rows). 8x8 per lane, waves split rows.
// 64 partial slices (chunk*4+wave), no atomics.
// ---------------------------------------------------------------------------
__global__ __launch_bounds__(256)
void kv_accum_kernel(const unsigned short* __restrict__ qkv, float* __restrict__ kvpart)
{
  __shared__ float ksf[16][64];
  __shared__ float vsf[16][64];
  const int t = threadIdx.x;
  const int bh = blockIdx.x, chunk = blockIdx.y;   // (64, 16)
  const int b = bh >> 3, h = bh & 7;
  const int base_row = b * 8192 + chunk * 512;
  const int lane = t & 63, wave = t >> 6;
  const int dk0 = (lane & 7) * 8, dv0 = (lane >> 3) * 8;
  const int half = t >> 7, tt = t & 127;
  const int sr = tt >> 3, u = tt & 7;
  const int col = (half ? 1024 : 512) + h * 64 + u * 8;
  const unsigned short* src = qkv + (size_t)(base_row + sr) * 1536 + col;
  float* dstlds = half ? &vsf[sr][u * 8] : &ksf[sr][u * 8];
  float acc[8][8] = {};

  for (int it = 0; it < 32; ++it) {
    __syncthreads();
    union { int4 v; unsigned short s[8]; } raw;
    raw.v = *(const int4*)(src + (size_t)it * 16 * 1536);
    float4 lo = { bf2f(raw.s[0]), bf2f(raw.s[1]), bf2f(raw.s[2]), bf2f(raw.s[3]) };
    float4 hi = { bf2f(raw.s[4]), bf2f(raw.s[5]), bf2f(raw.s[6]), bf2f(raw.s[7]) };
    *(float4*)dstlds = lo;
    *(float4*)(dstlds + 4) = hi;
    __syncthreads();
    #pragma unroll
    for (int rr = 0; rr < 4; ++rr) {
      int r = rr * 4 + wave;
      float4 ka = *(const float4*)&ksf[r][dk0];
      float4 kb = *(const float4*)&ksf[r][dk0 + 4];
      float4 va = *(const float4*)&vsf[r][dv0];
      float4 vb = *(const float4*)&vsf[r][dv0 + 4];
      float kf[8] = { ka.x, ka.y, ka.z, ka.w, kb.x, kb.y, kb.z, kb.w };
      float vf[8] = { va.x, va.y, va.z, va.w, vb.x, vb.y, vb.z, vb.w };
      #pragma unroll
      for (int i = 0; i < 8; ++i)
        #pragma unroll
        for (int j = 0; j < 8; ++j)
          acc[i][j] = fmaf(kf[i], vf[j], acc[i][j]);
    }
  }
  float* dst = kvpart + ((size_t)(chunk * 4 + wave) * 64 + bh) * 4096;
  #pragma unroll
  for (int i = 0; i < 8; ++i) {
    *(float4*)&dst[(dk0 + i) * 64 + dv0]     = (float4){ acc[i][0], acc[i][1], acc[i][2], acc[i][3] };
    *(float4*)&dst[(dk0 + i) * 64 + dv0 + 4] = (float4){ acc[i][4], acc[i][5], acc[i][6], acc[i][7] };
  }
}

// ---------------------------------------------------------------------------
// reduce 64 slice partials -> kvbuf[bh][4096]
// ---------------------------------------------------------------------------
__global__ __launch_bounds__(256)
void kv_reduce_kernel(const float* __restrict__ kvpart, float* __restrict__ kvbuf)
{
  const int bh = blockIdx.x, t = threadIdx.x;
  #pragma unroll
  for (int e = 0; e < 16; ++e) {
    int i = e * 256 + t;
    float s = 0.f;
    for (int c = 0; c < 64; ++c) s += kvpart[((size_t)c * 64 + bh) * 4096 + i];
    kvbuf[(size_t)bh * 4096 + i] = s;
  }
}

// ---------------------------------------------------------------------------
// W2t[b][d][(h,k)] = sum_v (kv[b,h][k][v]*gamma[h]/||kv row||) * Wo[h*64+v][d]
// ---------------------------------------------------------------------------
__global__ __launch_bounds__(256)
void build_w2t_kernel(const float* __restrict__ kvbuf, const float* __restrict__ Wo,
                      const float* __restrict__ gamma, unsigned short* __restrict__ W2t)
{
  __shared__ float WoS[512][16];
  const int b = blockIdx.x, dt = blockIdx.y;
  const int d0 = dt * 16;
  const int t = threadIdx.x;
  for (int i = 0; i < 32; ++i) {
    int flat = i * 256 + t;
    int rr_ = flat >> 4, c = flat & 15;
    WoS[rr_][c] = Wo[(size_t)rr_ * 512 + d0 + c];
  }
  __syncthreads();
  for (int rr = 0; rr < 2; ++rr) {
    int r = rr * 256 + t;
    int h = r >> 6, k = r & 63;
    const float* krow = kvbuf + ((size_t)b * 8 + h) * 4096 + (size_t)k * 64;
    float ss = 0.f;
    #pragma unroll
    for (int v = 0; v < 64; v += 4) {
      float4 x = *(const float4*)&krow[v];
      ss += x.x * x.x + x.y * x.y + x.z * x.z + x.w * x.w;
    }
    float scale = gamma[h] * rsqrtf(ss);
    f4v accv[4];
    #pragma unroll
    for (int j = 0; j < 4; ++j) accv[j] = (f4v){0.f, 0.f, 0.f, 0.f};
    for (int v = 0; v < 64; ++v) {
      float m = krow[v] * scale;
      const float* w = &WoS[h * 64 + v][0];
      #pragma unroll
      for (int j4 = 0; j4 < 4; ++j4) {
        float4 ww = *(const float4*)&w[j4 * 4];
        accv[j4][0] = fmaf(m, ww.x, accv[j4][0]);
        accv[j4][1] = fmaf(m, ww.y, accv[j4][1]);
        accv[j4][2] = fmaf(m, ww.z, accv[j4][2]);
        accv[j4][3] = fmaf(m, ww.w, accv[j4][3]);
      }
    }
    #pragma unroll
    for (int j = 0; j < 16; ++j)
      W2t[((size_t)b * 512 + d0 + j) * 512 + r] = f2bf(accv[j >> 2][j & 3]);
  }
}

// ---------------------------------------------------------------------------
// GEMM3: Y[b] = qhat[b] @ W2t[b]^T + bo, fp32 out. Swizzled staging as GEMM1.
// grid (4 nb, 512 rb).
// ---------------------------------------------------------------------------
__global__ __launch_bounds__(256, 2)
void gemm_out_kernel(const unsigned short* __restrict__ qkv,
                     const unsigned short* __restrict__ W2t,
                     const float* __restrict__ bo,
                     float* __restrict__ out)
{
  __shared__ short As[8192];
  __shared__ short Bs[8192];
  const int t = threadIdx.x;
  const int nb = blockIdx.x, rb = blockIdx.y;
  const int wave = t >> 6, lane = t & 63;
  const int wm = wave & 1, wn = wave >> 1;
  const int quad = lane >> 4, l16 = lane & 15;
  const int row0 = rb * 128;
  const int ncol0 = nb * 128;
  const unsigned short* Wb = W2t + (size_t)(rb >> 6) * 262144;

  const unsigned short* ap[4];
  const unsigned short* bp[4];
  #pragma unroll
  for (int i = 0; i < 4; ++i) {
    int s = i * 256 + t;
    int m = s >> 3;
    int kb = (s & 7) ^ (m & 7);
    ap[i] = qkv + (size_t)(row0 + m) * 1536 + kb * 8;
    bp[i] = Wb + (size_t)(ncol0 + m) * 512 + kb * 8;
  }

  f4v acc[4][4];
  #pragma unroll
  for (int i = 0; i < 4; ++i)
    #pragma unroll
    for (int j = 0; j < 4; ++j) acc[i][j] = (f4v){0.f, 0.f, 0.f, 0.f};

  for (int kt = 0; kt < 512; kt += 64) {
    __syncthreads();
    #pragma unroll
    for (int i = 0; i < 4; ++i) {
      int s8 = (i * 256 + t) * 8;
      gld16(ap[i] + kt, &As[s8]);
      gld16(bp[i] + kt, &Bs[s8]);
    }
    __syncthreads();
    #pragma unroll
    for (int ks = 0; ks < 2; ++ks) {
      s8v a[4], b[4];
      #pragma unroll
      for (int mi = 0; mi < 4; ++mi) {
        int r = wm * 64 + mi * 16 + l16;
        int slot = r * 8 + ((ks * 4 + quad) ^ (r & 7));
        a[mi] = *(const s8v*)&As[slot * 8];
      }
      #pragma unroll
      for (int nj = 0; nj < 4; ++nj) {
        int r = wn * 64 + nj * 16 + l16;
        int slot = r * 8 + ((ks * 4 + quad) ^ (r & 7));
        b[nj] = *(const s8v*)&Bs[slot * 8];
      }
      #pragma unroll
      for (int mi = 0; mi < 4; ++mi)
        #pragma unroll
        for (int nj = 0; nj < 4; ++nj)
          acc[mi][nj] = __builtin_amdgcn_mfma_f32_16x16x32_bf16(a[mi], b[nj], acc[mi][nj], 0, 0, 0);
    }
  }

  const int colbase = ncol0 + wn * 64;
  #pragma unroll
  for (int nj = 0; nj < 4; ++nj) {
    float bias = bo[colbase + nj * 16 + l16];
    #pragma unroll
    for (int mi = 0; mi < 4; ++mi)
      #pragma unroll
      for (int rr = 0; rr < 4; ++rr) {
        int row = row0 + wm * 64 + mi * 16 + quad * 4 + rr;
        int col = colbase + nj * 16 + l16;
        out[(size_t)row * 512 + col] = acc[mi][nj][rr] + bias;
      }
  }
}

// ---------------------------------------------------------------------------
extern "C" void kernel_launch(void* const* d_in, const int* in_sizes, int n_in,
                              void* d_out, int out_size, void* d_ws, size_t ws_size,
                              hipStream_t stream)
{
  (void)in_sizes; (void)n_in; (void)out_size; (void)ws_size;
  const float* X     = (const float*)d_in[0];
  const float* Wq    = (const float*)d_in[1];
  const float* bq    = (const float*)d_in[2];
  const float* Wk    = (const float*)d_in[3];
  const float* bk    = (const float*)d_in[4];
  const float* Wv    = (const float*)d_in[5];
  const float* bv    = (const float*)d_in[6];
  const float* Wo    = (const float*)d_in[7];
  const float* bo    = (const float*)d_in[8];
  const float* gamma = (const float*)d_in[9];

  char* ws = (char*)d_ws;
  unsigned short* qkv = (unsigned short*)ws;                         // 201326592 B
  unsigned short* Xbf = (unsigned short*)(ws + 201326592);           // 67108864 B
  float* kvpart = (float*)(ws + 201326592);                          // aliases Xbf (dead after gemm1): 64 MiB
  unsigned short* Wt  = (unsigned short*)(ws + 201326592 + 67108864);          // 1572864 B
  float* kvbuf        = (float*)(ws + 201326592 + 67108864 + 1572864);         // 1048576 B
  unsigned short* W2t = (unsigned short*)(ws + 201326592 + 67108864 + 1572864 + 1048576); // 4194304 B

  dim3 blk(256);
  convert_x_kernel<<<16384, blk, 0, stream>>>(X, Xbf);
  transpose_w_kernel<<<dim3(8, 24), blk, 0, stream>>>(Wq, Wk, Wv, Wt);
  gemm_qkv_kernel<<<dim3(12, 512), blk, 0, stream>>>(Xbf, Wt, bq, bk, bv, gamma, qkv);
  kv_accum_kernel<<<dim3(64, 16), blk, 0, stream>>>(qkv, kvpart);
  kv_reduce_kernel<<<64, blk, 0, stream>>>(kvpart, kvbuf);
  build_w2t_kernel<<<dim3(8, 32), blk, 0, stream>>>(kvbuf, Wo, gamma, W2t);
  gemm_out_kernel<<<dim3(4, 512), blk, 0, stream>>>(qkv, W2t, bo, (float*)d_out);
}